// Round 1
// baseline (535.473 us; speedup 1.0000x reference)
//
#include <hip/hip_runtime.h>

// WeightController: PI-style integral update + history-buffer shift.
//
// Outputs (concatenated flat in d_out, fp32):
//   [0 : 2048)                       weight_state_next
//   [2048 : 2048 + 8000*2048*5)      recording_next (history, batch, vars)
//
// recording_next[t]   = recording[t+1]        for t in [0, 7999)
// recording_next[7999, i, :] = (cv, ws_next, to_int, rl, e)
//
// Memory-bound: ~655 MB total HBM traffic -> ~104 us floor at 6.3 TB/s.
//
// R1: hipMemcpyAsync(DtoD) was serviced by an SDMA engine (~640 GB/s/dir;
// no kernel dispatch visible in rocprof). Replaced with a grid-strided
// float4 copy KERNEL fused with the controller update. Fill kernels on the
// same buffers sustain 6.4 TB/s, so a compute-blit copy should too.

#define N_BATCH     2048
#define N_HISTORY   8000
#define N_VARS      5
#define REF_V       (-0.2f)
#define K_I_V       (4.0f)
#define RATE_MAX_V  (0.01f)
#define RATE_MIN_V  (-0.02f)
#define LAMBDA_V    (1.5f)

// 7999 * 2048 * 5 floats = 81,909,760 floats = 20,477,440 float4 (exact).
#define COPY_VEC4   20477440u

__global__ __launch_bounds__(256) void wc_fused_kernel(
    const float* __restrict__ cv,
    const float* __restrict__ ws,
    const float* __restrict__ rec_in,
    float* __restrict__ out) {
    const unsigned tid    = blockIdx.x * blockDim.x + threadIdx.x;
    const unsigned stride = gridDim.x * blockDim.x;

    // ---- Bulk shift: recording[1:] -> recording_next[:7999] ----
    // src offset 10240 floats (40960 B), dst offset 2048 floats (8192 B):
    // both 16B-aligned, so float4 is exact (no scalar tail).
    const float4* __restrict__ src =
        reinterpret_cast<const float4*>(rec_in + (size_t)N_BATCH * N_VARS);
    float4* __restrict__ dst =
        reinterpret_cast<float4*>(out + N_BATCH);

    for (unsigned v = tid; v < COPY_VEC4; v += stride) {
        dst[v] = src[v];
    }

    // ---- Controller update + last record row (first 2048 threads) ----
    if (tid < N_BATCH) {
        const int i  = (int)tid;
        float c      = cv[i];
        float e      = REF_V - c;
        float to_int = K_I_V * e;
        float rl     = fminf(fmaxf(to_int, RATE_MIN_V), RATE_MAX_V);
        float wn     = fminf(fmaxf(ws[i] + rl, 0.0f), LAMBDA_V);

        out[i] = wn;  // weight_state_next

        float* rec = out + N_BATCH
                   + (size_t)(N_HISTORY - 1) * N_BATCH * N_VARS
                   + (size_t)i * N_VARS;
        rec[0] = c;
        rec[1] = wn;
        rec[2] = to_int;
        rec[3] = rl;
        rec[4] = e;
    }
}

extern "C" void kernel_launch(void* const* d_in, const int* in_sizes, int n_in,
                              void* d_out, int out_size, void* d_ws, size_t ws_size,
                              hipStream_t stream) {
    const float* cv  = (const float*)d_in[0];   // controlled_variable (2048,)
    const float* ws  = (const float*)d_in[1];   // weight_state (2048,)
    const float* rec = (const float*)d_in[2];   // recording (8000, 2048, 5)
    float* out = (float*)d_out;

    // Memory-bound streaming: cap grid at 8 blocks/CU * 256 CUs = 2048,
    // grid-stride the rest (~39 float4 iterations per thread).
    wc_fused_kernel<<<2048, 256, 0, stream>>>(cv, ws, rec, out);
}